// Round 1
// baseline (292.189 us; speedup 1.0000x reference)
//
#include <hip/hip_runtime.h>
#include <hip/hip_cooperative_groups.h>

namespace cg = cooperative_groups;

typedef __attribute__((ext_vector_type(8))) short short8;
typedef __attribute__((ext_vector_type(4))) float floatx4;

// Problem constants
#define NEXP   36          // 12 tempers * 3 ops
#define NTOK   1024        // 128 batch * 8 patches
#define HOPS   4
#define NBLK   256         // cooperative grid (<= 512 co-resident at 1024thr/128VGPR)

// Workspace layout (bytes)
#define OFF_STATE   0u          // 1024*256*4      = 1,048,576
#define OFF_W1B     1048576u    // 36*65536*2      = 4,718,592 (bf16, B-frag swizzled)
#define OFF_W2B     5767168u    // 36*65536*2      = 4,718,592
#define OFF_C1      10485760u   // 36*256*4        = 36,864
#define OFF_COUNTS  10522624u   // 4*36*4          = 576
#define OFF_LISTS   10523264u   // 4*36*1024*4     = 589,824 (end ~11.1 MB)

__device__ __forceinline__ unsigned short f2bf(float f) {
    unsigned u = __float_as_uint(f);
    u += 0x7FFFu + ((u >> 16) & 1u);   // round-to-nearest-even
    return (unsigned short)(u >> 16);
}

// ---------------------------------------------------------------------------
// ONE cooperative kernel.
//   Phase 0: task loop over 613 tasks (task 0 = routing (overlapped first),
//            tasks 1..36 = c1, tasks 37..612 = W1/W2 -> bf16 frag convert).
//   grid.sync()
//   Phase 1: block b < 36 owns expert b. B-fragments loaded into 64 VGPRs
//            ONCE and reused across ALL FOUR HOPS (this removes the 4x
//            per-hop 18-23 MB weight refetch of the multi-kernel version).
//            grid.sync() between hops for cross-XCD state visibility.
//   Phase 2: blocks 0..127 do mean-pool + LayerNorm + head for one batch row.
// MFMA maps (m89): A[m=l&15][k=(l>>4)*8+i]; D col=l&15, row=(l>>4)*4+reg.
// ---------------------------------------------------------------------------
__global__ __launch_bounds__(1024, 4) void fused_kernel(
    const float* __restrict__ x, const float* __restrict__ W1,
    const float* __restrict__ b1, const float* __restrict__ W2,
    const float* __restrict__ b2, const float* __restrict__ op_emb,
    const float* __restrict__ ln_g, const float* __restrict__ ln_b,
    const float* __restrict__ Wt, const float* __restrict__ bt,
    const int* __restrict__ tempers, const int* __restrict__ ops,
    unsigned short* __restrict__ W1b, unsigned short* __restrict__ W2b,
    float* __restrict__ c1, int* __restrict__ counts, int* __restrict__ lists,
    float* __restrict__ state, float* __restrict__ out)
{
    cg::grid_group grid = cg::this_grid();
    const int bid = blockIdx.x;
    const int t   = threadIdx.x;

    __shared__ unsigned short Ab[4096];   // 8 KB, A-frag bf16
    __shared__ unsigned short Hb[4096];   // 8 KB
    __shared__ int   toks[16];
    __shared__ int   lc[HOPS * NEXP];     // routing counters
    __shared__ float pool[4][256];        // final: partial pooled sums
    __shared__ float red[8];
    __shared__ float stats[2];
    __shared__ float pr[40];

    // ================= Phase 0: convert + c1 + routing =================
    for (int task = bid; task < 613; task += NBLK) {
        if (task == 0) {
            // ---- routing (single block; cumulative-halt semantics) ----
            if (t < HOPS * NEXP) lc[t] = 0;
            __syncthreads();
            if (t < 256) {
                for (int q = 0; q < 4; q++) {
                    int n = q * 256 + t;
                    bool act = true;
                    for (int hop = 0; hop < HOPS; hop++) {
                        int tt = tempers[hop * NTOK + n];
                        int oo = ops[hop * NTOK + n];
                        act = act && (tt != 12);       // 12 == halt; sticky
                        if (act) {
                            int eidx = tt * 3 + oo;
                            int pos = atomicAdd(&lc[hop * NEXP + eidx], 1);
                            lists[(hop * NEXP + eidx) * NTOK + pos] = n;
                        }
                    }
                }
            }
            __syncthreads();
            if (t < HOPS * NEXP) counts[t] = lc[t];
        } else if (task <= 36) {
            // ---- c1[e][j] = b1 + emb @ W1_embrows (fp32) ----
            const int e = task - 1;
            if (t < 256) {
                float acc = b1[e * 256 + t];
                const float* wp = W1 + e * 98304 + 65536;  // emb rows of W1[e]
                #pragma unroll 4
                for (int k = 0; k < 128; k++)
                    acc += op_emb[e * 128 + k] * wp[k * 256 + t];
                c1[e * 256 + t] = acc;
            }
        } else {
            // ---- weight convert + swizzle: task = (mat, e, kb), 1024 thr ----
            const int ct  = task - 37;
            const int mat = ct / 288;          // 0: W1, 1: W2
            const int id  = ct % 288;
            const int e   = id / 8;
            const int kb  = id % 8;
            const float* src = mat ? (W2 + e * 65536) : (W1 + e * 98304);
            unsigned short* dst = (mat ? W2b : W1b) + e * 65536;
            const int j  = (t >> 8) * 64 + (t & 63);
            const int ks = ((t >> 6) & 3) * 8;
            short8 v;
            #pragma unroll
            for (int i = 0; i < 8; i++)
                v[i] = (short)f2bf(src[(kb * 32 + ks + i) * 256 + j]);
            *(short8*)(dst + (kb * 256 + j) * 32 + ks) = v;
        }
    }
    grid.sync();

    // ================= Phase 1: hops, expert-stationary =================
    const int l = t & 63, w = t >> 6;      // wave 0..15
    const int col = l & 15, g = l >> 4;
    const int j = w * 16 + col;            // this wave's output column

    const int e = bid;
    short8 B1f[8], B2f[8];
    float cv = 0.f, bv = 0.f;
    if (e < NEXP) {
        // ---- B-frag preload ONCE, lives in 64 VGPRs across all hops ----
        const unsigned short* Wp  = W1b + e * 65536;
        const unsigned short* Wp2 = W2b + e * 65536;
        #pragma unroll
        for (int kb = 0; kb < 8; kb++) {
            B1f[kb] = *(const short8*)(Wp  + (kb * 256 + j) * 32 + g * 8);
            B2f[kb] = *(const short8*)(Wp2 + (kb * 256 + j) * 32 + g * 8);
        }
        cv = c1[e * 256 + j];
        bv = b2[e * 256 + j];
    }

    for (int hop = 0; hop < HOPS; hop++) {
        if (e < NEXP) {
            const int n_e = counts[hop * NEXP + e];
            const float* src = hop ? state : x;
            for (int m0 = 0; m0 < n_e; m0 += 16) {
                const int mact = min(16, n_e - m0);
                __syncthreads();               // toks reuse guard across tiles
                if (t < 16)
                    toks[t] = (t < mact)
                            ? lists[(hop * NEXP + e) * NTOK + m0 + t] : 0;
                __syncthreads();
                // ---- stage A tile: src rows (f32) -> bf16 A-frag layout ----
                {
                    int m = t >> 6;            // one wave per token row
                    int k = (t & 63) * 4;
                    float4 v = make_float4(0.f, 0.f, 0.f, 0.f);
                    if (m < mact) v = *(const float4*)(src + toks[m] * 256 + k);
                    int kb = k >> 5, gg = (k >> 3) & 3, i = k & 7;
                    unsigned short* d = Ab + kb * 512 + (gg * 16 + m) * 8 + i;
                    d[0] = f2bf(v.x); d[1] = f2bf(v.y);
                    d[2] = f2bf(v.z); d[3] = f2bf(v.w);
                }
                __syncthreads();
                // ---- GEMM1 (weights in registers) ----
                floatx4 acc = (floatx4){cv, cv, cv, cv};
                #pragma unroll
                for (int kb = 0; kb < 8; kb++) {
                    short8 a = *(const short8*)(Ab + kb * 512 + l * 8);
                    acc = __builtin_amdgcn_mfma_f32_16x16x32_bf16(a, B1f[kb], acc, 0, 0, 0);
                }
                // ---- epilogue 1: relu -> Hb (h-dim becomes K) ----
                {
                    int kb2 = j >> 5, g2 = (j >> 3) & 3, i2 = j & 7;
                    #pragma unroll
                    for (int r = 0; r < 4; r++) {
                        int m = g * 4 + r;
                        float vv = acc[r];
                        vv = vv > 0.f ? vv : 0.f;
                        Hb[kb2 * 512 + (g2 * 16 + m) * 8 + i2] = f2bf(vv);
                    }
                }
                __syncthreads();
                // ---- GEMM2 ----
                floatx4 acc2 = (floatx4){bv, bv, bv, bv};
                #pragma unroll
                for (int kb = 0; kb < 8; kb++) {
                    short8 a = *(const short8*)(Hb + kb * 512 + l * 8);
                    acc2 = __builtin_amdgcn_mfma_f32_16x16x32_bf16(a, B2f[kb], acc2, 0, 0, 0);
                }
                // ---- epilogue 2: relu -> state (f32), only real rows ----
                #pragma unroll
                for (int r = 0; r < 4; r++) {
                    int m = g * 4 + r;
                    if (m < mact) {
                        float vv = acc2[r];
                        state[toks[m] * 256 + j] = vv > 0.f ? vv : 0.f;
                    }
                }
            }
        }
        grid.sync();                           // state visible across XCDs
    }

    // ================= Phase 2: pool + LN + head =================
    const int b = bid;
    if (b < 128) {
        // pooling: 1024 threads = 4 groups x 256 cols, 2 patches per group
        {
            const int c = t & 255, grp = t >> 8;
            float s = 0.f;
            #pragma unroll
            for (int pp = 0; pp < 2; pp++) {
                int n = b * 8 + grp * 2 + pp;
                // tokens halted at hop 0 were never written to state -> read x
                const float* rowsrc = (tempers[n] != 12) ? state : x;
                s += rowsrc[n * 256 + c];
            }
            pool[grp][c] = s;
        }
        __syncthreads();
        float pooled = 0.f;
        if (t < 256) {
            pooled = (pool[0][t] + pool[1][t] + pool[2][t] + pool[3][t]) * 0.125f;
            float v1 = pooled, v2 = pooled * pooled;
            #pragma unroll
            for (int off = 32; off; off >>= 1) {
                v1 += __shfl_down(v1, off);
                v2 += __shfl_down(v2, off);
            }
            const int wq = t >> 6, lq = t & 63;
            if (lq == 0) { red[wq] = v1; red[4 + wq] = v2; }
        }
        __syncthreads();
        if (t == 0) {
            float su = red[0] + red[1] + red[2] + red[3];
            float sq = red[4] + red[5] + red[6] + red[7];
            float mu = su * (1.0f / 256.0f);
            float var = sq * (1.0f / 256.0f) - mu * mu;
            stats[0] = mu;
            stats[1] = rsqrtf(var + 1e-5f);
        }
        __syncthreads();
        if (t < 256) {
            float normed = (pooled - stats[0]) * stats[1] * ln_g[t] + ln_b[t];
            const int wq = t >> 6, lq = t & 63;
            #pragma unroll
            for (int c = 0; c < 10; c++) {
                float pv = normed * Wt[t * 10 + c];
                #pragma unroll
                for (int off = 32; off; off >>= 1) pv += __shfl_down(pv, off);
                if (lq == 0) pr[wq * 10 + c] = pv;
            }
        }
        __syncthreads();
        if (t < 10)
            out[b * 10 + t] = pr[t] + pr[10 + t] + pr[20 + t] + pr[30 + t] + bt[t];
    }
}

extern "C" void kernel_launch(void* const* d_in, const int* in_sizes, int n_in,
                              void* d_out, int out_size, void* d_ws, size_t ws_size,
                              hipStream_t stream)
{
    const float* x      = (const float*)d_in[0];
    const float* W1     = (const float*)d_in[1];
    const float* b1     = (const float*)d_in[2];
    const float* W2     = (const float*)d_in[3];
    const float* b2     = (const float*)d_in[4];
    const float* op_emb = (const float*)d_in[5];
    const float* ln_g   = (const float*)d_in[6];
    const float* ln_b   = (const float*)d_in[7];
    const float* Wt     = (const float*)d_in[8];
    const float* bt     = (const float*)d_in[9];
    const int* tempers  = (const int*)d_in[10];
    const int* ops      = (const int*)d_in[11];

    char* ws = (char*)d_ws;
    float* state          = (float*)(ws + OFF_STATE);
    unsigned short* W1b   = (unsigned short*)(ws + OFF_W1B);
    unsigned short* W2b   = (unsigned short*)(ws + OFF_W2B);
    float* c1             = (float*)(ws + OFF_C1);
    int* counts           = (int*)(ws + OFF_COUNTS);
    int* lists            = (int*)(ws + OFF_LISTS);
    float* out            = (float*)d_out;

    void* args[] = {
        (void*)&x, (void*)&W1, (void*)&b1, (void*)&W2, (void*)&b2,
        (void*)&op_emb, (void*)&ln_g, (void*)&ln_b, (void*)&Wt, (void*)&bt,
        (void*)&tempers, (void*)&ops, (void*)&W1b, (void*)&W2b, (void*)&c1,
        (void*)&counts, (void*)&lists, (void*)&state, (void*)&out
    };
    hipLaunchCooperativeKernel((void*)fused_kernel, dim3(NBLK), dim3(1024),
                               args, 0, stream);
}

// Round 2
// 223.438 us; speedup vs baseline: 1.3077x; 1.3077x over previous
//
#include <hip/hip_runtime.h>
#include <hip/hip_cooperative_groups.h>

namespace cg = cooperative_groups;

typedef __attribute__((ext_vector_type(8))) short short8;
typedef __attribute__((ext_vector_type(4))) float floatx4;

// Problem constants
#define NEXP   36          // 12 tempers * 3 ops
#define NTOK   1024        // 128 batch * 8 patches
#define HOPS   4
#define NBLK   128         // cooperative grid; 1 block/CU at 1024thr -> co-resident

// Workspace layout (bytes)
#define OFF_STATE   0u          // 1024*256*4      = 1,048,576
#define OFF_W1B     1048576u    // 36*65536*2      = 4,718,592 (bf16, B-frag swizzled)
#define OFF_W2B     5767168u    // 36*65536*2      = 4,718,592
#define OFF_C1      10485760u   // 36*256*4        = 36,864
#define OFF_COUNTS  10522624u   // 4*36*4          = 576
#define OFF_LISTS   10523264u   // 4*36*1024*4     = 589,824 (end ~11.1 MB)

__device__ __forceinline__ unsigned short f2bf(float f) {
    unsigned u = __float_as_uint(f);
    u += 0x7FFFu + ((u >> 16) & 1u);   // round-to-nearest-even
    return (unsigned short)(u >> 16);
}

// ---------------------------------------------------------------------------
// ONE cooperative kernel.
//   Phase 0: 613 tasks over 128 blocks (task 0 = routing, 1..36 = c1,
//            37..612 = W1/W2 -> bf16 frag convert).
//   grid.sync()
//   Phase 1: bid = expert*2 + slot (experts 0..35 on bids 0..71).
//            B-fragments loaded into 64 VGPRs ONCE, PINNED via asm "+v"
//            (r1 post-mortem: VGPR_Count=52 proved the compiler sank the
//            loads into the MFMA loop -> every MFMA serialized on a ~900cy
//            cross-XCD load; the pin makes the asm the producer so the
//            values MUST stay register-resident across all 4 hops).
//            Slot s processes tiles m0 = s*16, s*16+32, ... (2-way tile
//            parallelism per expert).
//   Phase 2: blocks 0..127 mean-pool + LayerNorm + head, one batch row each.
// MFMA maps (m89): A[m=l&15][k=(l>>4)*8+i]; D col=l&15, row=(l>>4)*4+reg.
// ---------------------------------------------------------------------------
__global__ __launch_bounds__(1024, 4) void fused_kernel(
    const float* __restrict__ x, const float* __restrict__ W1,
    const float* __restrict__ b1, const float* __restrict__ W2,
    const float* __restrict__ b2, const float* __restrict__ op_emb,
    const float* __restrict__ ln_g, const float* __restrict__ ln_b,
    const float* __restrict__ Wt, const float* __restrict__ bt,
    const int* __restrict__ tempers, const int* __restrict__ ops,
    unsigned short* __restrict__ W1b, unsigned short* __restrict__ W2b,
    float* __restrict__ c1, int* __restrict__ counts, int* __restrict__ lists,
    float* __restrict__ state, float* __restrict__ out)
{
    cg::grid_group grid = cg::this_grid();
    const int bid = blockIdx.x;
    const int t   = threadIdx.x;

    __shared__ unsigned short Ab[4096];   // 8 KB, A-frag bf16
    __shared__ unsigned short Hb[4096];   // 8 KB
    __shared__ int   toks[16];
    __shared__ int   lc[HOPS * NEXP];     // routing counters
    __shared__ float pool[4][256];        // final: partial pooled sums
    __shared__ float red[8];
    __shared__ float stats[2];
    __shared__ float pr[40];

    // ================= Phase 0: convert + c1 + routing =================
    for (int task = bid; task < 613; task += NBLK) {
        if (task == 0) {
            // ---- routing (single block; cumulative-halt semantics) ----
            if (t < HOPS * NEXP) lc[t] = 0;
            __syncthreads();
            if (t < 256) {
                for (int q = 0; q < 4; q++) {
                    int n = q * 256 + t;
                    bool act = true;
                    for (int hop = 0; hop < HOPS; hop++) {
                        int tt = tempers[hop * NTOK + n];
                        int oo = ops[hop * NTOK + n];
                        act = act && (tt != 12);       // 12 == halt; sticky
                        if (act) {
                            int eidx = tt * 3 + oo;
                            int pos = atomicAdd(&lc[hop * NEXP + eidx], 1);
                            lists[(hop * NEXP + eidx) * NTOK + pos] = n;
                        }
                    }
                }
            }
            __syncthreads();
            if (t < HOPS * NEXP) counts[t] = lc[t];
        } else if (task <= 36) {
            // ---- c1[e][j] = b1 + emb @ W1_embrows (fp32) ----
            const int e = task - 1;
            if (t < 256) {
                float acc = b1[e * 256 + t];
                const float* wp = W1 + e * 98304 + 65536;  // emb rows of W1[e]
                #pragma unroll 4
                for (int k = 0; k < 128; k++)
                    acc += op_emb[e * 128 + k] * wp[k * 256 + t];
                c1[e * 256 + t] = acc;
            }
        } else {
            // ---- weight convert + swizzle: task = (mat, e, kb), 1024 thr ----
            const int ct  = task - 37;
            const int mat = ct / 288;          // 0: W1, 1: W2
            const int id  = ct % 288;
            const int e   = id / 8;
            const int kb  = id % 8;
            const float* src = mat ? (W2 + e * 65536) : (W1 + e * 98304);
            unsigned short* dst = (mat ? W2b : W1b) + e * 65536;
            const int j  = (t >> 8) * 64 + (t & 63);
            const int ks = ((t >> 6) & 3) * 8;
            short8 v;
            #pragma unroll
            for (int i = 0; i < 8; i++)
                v[i] = (short)f2bf(src[(kb * 32 + ks + i) * 256 + j]);
            *(short8*)(dst + (kb * 256 + j) * 32 + ks) = v;
        }
    }
    grid.sync();

    // ================= Phase 1: hops, expert-stationary =================
    const int l = t & 63, w = t >> 6;      // wave 0..15
    const int col = l & 15, g = l >> 4;
    const int j = w * 16 + col;            // this wave's output column

    const int e    = bid >> 1;             // expert 0..63 (work if < 36)
    const int slot = bid & 1;              // tile-slot within expert
    short8 B1f[8], B2f[8];
    float cv = 0.f, bv = 0.f;
    if (e < NEXP) {
        // ---- B-frag preload ONCE; pinned to VGPRs for all hops ----
        const unsigned short* Wp  = W1b + e * 65536;
        const unsigned short* Wp2 = W2b + e * 65536;
        #pragma unroll
        for (int kb = 0; kb < 8; kb++) {
            B1f[kb] = *(const short8*)(Wp  + (kb * 256 + j) * 32 + g * 8);
            B2f[kb] = *(const short8*)(Wp2 + (kb * 256 + j) * 32 + g * 8);
        }
        #pragma unroll
        for (int kb = 0; kb < 8; kb++) {
            asm volatile("" : "+v"(B1f[kb]));   // forbid remat-as-load
            asm volatile("" : "+v"(B2f[kb]));
        }
        cv = c1[e * 256 + j];
        bv = b2[e * 256 + j];
    }

    for (int hop = 0; hop < HOPS; hop++) {
        if (e < NEXP) {
            const int n_e = counts[hop * NEXP + e];
            const float* src = hop ? state : x;
            for (int m0 = slot * 16; m0 < n_e; m0 += 32) {
                const int mact = min(16, n_e - m0);
                __syncthreads();               // toks reuse guard across tiles
                if (t < 16)
                    toks[t] = (t < mact)
                            ? lists[(hop * NEXP + e) * NTOK + m0 + t] : 0;
                __syncthreads();
                // ---- stage A tile: src rows (f32) -> bf16 A-frag layout ----
                {
                    int m = t >> 6;            // one wave per token row
                    int k = (t & 63) * 4;
                    float4 v = make_float4(0.f, 0.f, 0.f, 0.f);
                    if (m < mact) v = *(const float4*)(src + toks[m] * 256 + k);
                    int kb = k >> 5, gg = (k >> 3) & 3, i = k & 7;
                    unsigned short* d = Ab + kb * 512 + (gg * 16 + m) * 8 + i;
                    d[0] = f2bf(v.x); d[1] = f2bf(v.y);
                    d[2] = f2bf(v.z); d[3] = f2bf(v.w);
                }
                __syncthreads();
                // ---- GEMM1 (weights in registers) ----
                floatx4 acc = (floatx4){cv, cv, cv, cv};
                #pragma unroll
                for (int kb = 0; kb < 8; kb++) {
                    short8 a = *(const short8*)(Ab + kb * 512 + l * 8);
                    acc = __builtin_amdgcn_mfma_f32_16x16x32_bf16(a, B1f[kb], acc, 0, 0, 0);
                }
                // ---- epilogue 1: relu -> Hb (h-dim becomes K) ----
                {
                    int kb2 = j >> 5, g2 = (j >> 3) & 3, i2 = j & 7;
                    #pragma unroll
                    for (int r = 0; r < 4; r++) {
                        int m = g * 4 + r;
                        float vv = acc[r];
                        vv = vv > 0.f ? vv : 0.f;
                        Hb[kb2 * 512 + (g2 * 16 + m) * 8 + i2] = f2bf(vv);
                    }
                }
                __syncthreads();
                // ---- GEMM2 ----
                floatx4 acc2 = (floatx4){bv, bv, bv, bv};
                #pragma unroll
                for (int kb = 0; kb < 8; kb++) {
                    short8 a = *(const short8*)(Hb + kb * 512 + l * 8);
                    acc2 = __builtin_amdgcn_mfma_f32_16x16x32_bf16(a, B2f[kb], acc2, 0, 0, 0);
                }
                // ---- epilogue 2: relu -> state (f32), only real rows ----
                #pragma unroll
                for (int r = 0; r < 4; r++) {
                    int m = g * 4 + r;
                    if (m < mact) {
                        float vv = acc2[r];
                        state[toks[m] * 256 + j] = vv > 0.f ? vv : 0.f;
                    }
                }
            }
        }
        grid.sync();                           // state visible across XCDs
    }

    // ================= Phase 2: pool + LN + head =================
    const int b = bid;
    {
        // pooling: 1024 threads = 4 groups x 256 cols, 2 patches per group
        {
            const int c = t & 255, grp = t >> 8;
            float s = 0.f;
            #pragma unroll
            for (int pp = 0; pp < 2; pp++) {
                int n = b * 8 + grp * 2 + pp;
                // tokens halted at hop 0 were never written to state -> read x
                const float* rowsrc = (tempers[n] != 12) ? state : x;
                s += rowsrc[n * 256 + c];
            }
            pool[grp][c] = s;
        }
        __syncthreads();
        float pooled = 0.f;
        if (t < 256) {
            pooled = (pool[0][t] + pool[1][t] + pool[2][t] + pool[3][t]) * 0.125f;
            float v1 = pooled, v2 = pooled * pooled;
            #pragma unroll
            for (int off = 32; off; off >>= 1) {
                v1 += __shfl_down(v1, off);
                v2 += __shfl_down(v2, off);
            }
            const int wq = t >> 6, lq = t & 63;
            if (lq == 0) { red[wq] = v1; red[4 + wq] = v2; }
        }
        __syncthreads();
        if (t == 0) {
            float su = red[0] + red[1] + red[2] + red[3];
            float sq = red[4] + red[5] + red[6] + red[7];
            float mu = su * (1.0f / 256.0f);
            float var = sq * (1.0f / 256.0f) - mu * mu;
            stats[0] = mu;
            stats[1] = rsqrtf(var + 1e-5f);
        }
        __syncthreads();
        if (t < 256) {
            float normed = (pooled - stats[0]) * stats[1] * ln_g[t] + ln_b[t];
            const int wq = t >> 6, lq = t & 63;
            #pragma unroll
            for (int c = 0; c < 10; c++) {
                float pv = normed * Wt[t * 10 + c];
                #pragma unroll
                for (int off = 32; off; off >>= 1) pv += __shfl_down(pv, off);
                if (lq == 0) pr[wq * 10 + c] = pv;
            }
        }
        __syncthreads();
        if (t < 10)
            out[b * 10 + t] = pr[t] + pr[10 + t] + pr[20 + t] + pr[30 + t] + bt[t];
    }
}

extern "C" void kernel_launch(void* const* d_in, const int* in_sizes, int n_in,
                              void* d_out, int out_size, void* d_ws, size_t ws_size,
                              hipStream_t stream)
{
    const float* x      = (const float*)d_in[0];
    const float* W1     = (const float*)d_in[1];
    const float* b1     = (const float*)d_in[2];
    const float* W2     = (const float*)d_in[3];
    const float* b2     = (const float*)d_in[4];
    const float* op_emb = (const float*)d_in[5];
    const float* ln_g   = (const float*)d_in[6];
    const float* ln_b   = (const float*)d_in[7];
    const float* Wt     = (const float*)d_in[8];
    const float* bt     = (const float*)d_in[9];
    const int* tempers  = (const int*)d_in[10];
    const int* ops      = (const int*)d_in[11];

    char* ws = (char*)d_ws;
    float* state          = (float*)(ws + OFF_STATE);
    unsigned short* W1b   = (unsigned short*)(ws + OFF_W1B);
    unsigned short* W2b   = (unsigned short*)(ws + OFF_W2B);
    float* c1             = (float*)(ws + OFF_C1);
    int* counts           = (int*)(ws + OFF_COUNTS);
    int* lists            = (int*)(ws + OFF_LISTS);
    float* out            = (float*)d_out;

    void* args[] = {
        (void*)&x, (void*)&W1, (void*)&b1, (void*)&W2, (void*)&b2,
        (void*)&op_emb, (void*)&ln_g, (void*)&ln_b, (void*)&Wt, (void*)&bt,
        (void*)&tempers, (void*)&ops, (void*)&W1b, (void*)&W2b, (void*)&c1,
        (void*)&counts, (void*)&lists, (void*)&state, (void*)&out
    };
    hipLaunchCooperativeKernel((void*)fused_kernel, dim3(NBLK), dim3(1024),
                               args, 0, stream);
}

// Round 3
// 138.124 us; speedup vs baseline: 2.1154x; 1.6177x over previous
//
#include <hip/hip_runtime.h>

typedef __attribute__((ext_vector_type(8))) short short8;
typedef __attribute__((ext_vector_type(4))) float floatx4;

// Problem constants
#define NEXP   36          // 12 tempers * 3 ops
#define NTOK   1024        // 128 batch * 8 patches
#define HOPS   4

// Workspace layout (bytes)
#define OFF_STATE   0u          // 1024*256*4      = 1,048,576
#define OFF_W1B     1048576u    // 36*65536*2      = 4,718,592 (bf16, B-frag swizzled)
#define OFF_W2B     5767168u    // 36*65536*2      = 4,718,592
#define OFF_C1      10485760u   // 36*256*4        = 36,864
#define OFF_COUNTS  10522624u   // 4*36*4          = 576
#define OFF_LISTS   10523264u   // 4*36*1024*4     = 589,824 (end ~11.1 MB)

__device__ __forceinline__ unsigned short f2bf(float f) {
    unsigned u = __float_as_uint(f);
    u += 0x7FFFu + ((u >> 16) & 1u);   // round-to-nearest-even
    return (unsigned short)(u >> 16);
}

// ---------------------------------------------------------------------------
// PREP. Multi-kernel revert (r2 post-mortem: coop fusion = 118us GPU vs ~35us
// for the r0 multi-kernel path; the ~106us JSON-vs-kernel gap is fixed harness
// overhead, so kernel-sum is the only lever).
// XCD-affinity mapping: every block touching expert e satisfies bid%8 == e%8,
// in THIS kernel (weight-convert writes, c1) and in all 4 hop launches
// (reads). If blockIdx->XCD is round-robin %8, expert weights stay resident
// in one XCD's L2 across the whole launch sequence -> per-hop 128KB/block
// B-frag preload becomes L2 hits instead of HBM/L3 refetch.
//  bids [0,2880)   : weight convert. r=bid%8, q=bid/8, e=r+8*(q/64) (skip
//                    e>=36), sub=q%64 -> mat=sub>>5, kb=(sub&31)>>2, jt=sub&3.
//  bids [2880,2916): c1[e], e=bid-2880 (2880%8==0 -> bid%8==e%8).
//  bid  2916       : routing (no job compaction needed anymore).
// ---------------------------------------------------------------------------
__global__ __launch_bounds__(256) void prep_kernel(
    const float* __restrict__ W1, const float* __restrict__ b1,
    const float* __restrict__ W2, const float* __restrict__ op_emb,
    const int* __restrict__ tempers, const int* __restrict__ ops,
    unsigned short* __restrict__ W1b, unsigned short* __restrict__ W2b,
    float* __restrict__ c1, int* __restrict__ counts, int* __restrict__ lists)
{
    const int bid = blockIdx.x;
    const int t = threadIdx.x;

    if (bid < 2880) {
        // ---- weight convert + swizzle (XCD-affine) ----
        const int r  = bid & 7;
        const int q  = bid >> 3;
        const int e  = r + 8 * (q >> 6);
        if (e >= NEXP) return;             // 576 idle blocks, negligible
        const int sub = q & 63;
        const int mat = sub >> 5;          // 0: W1, 1: W2
        const int s2  = sub & 31;
        const int kb  = s2 >> 2;
        const int jt  = s2 & 3;
        const float* src = mat ? (W2 + e * 65536) : (W1 + e * 98304);
        unsigned short* dst = (mat ? W2b : W1b) + e * 65536;
        const int j  = jt * 64 + (t & 63);
        const int ks = (t >> 6) * 8;       // 8 consecutive k per thread
        short8 v;
        #pragma unroll
        for (int i = 0; i < 8; i++)
            v[i] = (short)f2bf(src[(kb * 32 + ks + i) * 256 + j]);  // coalesced across j
        *(short8*)(dst + (kb * 256 + j) * 32 + ks) = v;
    } else if (bid < 2916) {
        // ---- c1 precompute (fp32), XCD-affine ----
        const int e = bid - 2880;
        __shared__ float eb[128];
        if (t < 128) eb[t] = op_emb[e * 128 + t];
        __syncthreads();
        float acc = b1[e * 256 + t];
        const float* wp = W1 + e * 98304 + 65536;  // emb rows of W1[e]
        #pragma unroll 4
        for (int k = 0; k < 128; k++)
            acc += eb[k] * wp[k * 256 + t];
        c1[e * 256 + t] = acc;
    } else {
        // ---- routing (single block; cumulative-halt semantics) ----
        __shared__ int lc[HOPS * NEXP];
        if (t < HOPS * NEXP) lc[t] = 0;
        __syncthreads();
        for (int q = 0; q < 4; q++) {
            int n = q * 256 + t;
            bool act = true;
            for (int hop = 0; hop < HOPS; hop++) {
                int tt = tempers[hop * NTOK + n];
                int oo = ops[hop * NTOK + n];
                act = act && (tt != 12);       // 12 == halt; sticky
                if (act) {
                    int e = tt * 3 + oo;
                    int pos = atomicAdd(&lc[hop * NEXP + e], 1);
                    lists[(hop * NEXP + e) * NTOK + pos] = n;
                }
            }
        }
        __syncthreads();
        if (t < HOPS * NEXP) counts[t] = lc[t];
    }
}

// ---------------------------------------------------------------------------
// HOP: expert-stationary. bid -> e = bid%40, slot = bid/40 (4 slots).
// bid%8 == e%8 (40 ≡ 0 mod 8) -> same XCD as the prep writes and as the same
// expert's block in every other hop launch: weight preload should L2-hit.
// Slot s handles tiles m0 = s*16, s*16+64, ... Early-exit BEFORE the 128KB
// preload when the slot has no tiles (cuts ~half the weight traffic).
// __launch_bounds__(1024,4): 128-VGPR budget so the 64-VGPR B-frag preload
// stays register-resident; asm "+v" pin forbids remat-as-load.
// MFMA maps (m89): A[m=l&15][k=(l>>4)*8+i]; D col=l&15, row=(l>>4)*4+reg.
// ---------------------------------------------------------------------------
__global__ __launch_bounds__(1024, 4) void hop_kernel(
    const float* __restrict__ src, float* __restrict__ state,
    const unsigned short* __restrict__ W1b,
    const unsigned short* __restrict__ W2b,
    const float* __restrict__ c1, const float* __restrict__ b2,
    const int* __restrict__ counts, const int* __restrict__ lists, int hop)
{
    const int e    = blockIdx.x % 40;
    const int slot = blockIdx.x / 40;
    if (e >= NEXP) return;
    const int n_e = counts[hop * NEXP + e];
    if (slot * 16 >= n_e) return;          // no tile for this slot

    const int t = threadIdx.x;
    const int l = t & 63, w = t >> 6;      // wave 0..15
    const int col = l & 15, g = l >> 4;
    const int j = w * 16 + col;            // this wave's output column

    // ---- preload B-frags for both GEMMs (register-resident) ----
    const unsigned short* Wp  = W1b + e * 65536;
    const unsigned short* Wp2 = W2b + e * 65536;
    short8 B1[8], B2[8];
    #pragma unroll
    for (int kb = 0; kb < 8; kb++) {
        B1[kb] = *(const short8*)(Wp  + (kb * 256 + j) * 32 + g * 8);
        B2[kb] = *(const short8*)(Wp2 + (kb * 256 + j) * 32 + g * 8);
    }
    #pragma unroll
    for (int kb = 0; kb < 8; kb++) {
        asm volatile("" : "+v"(B1[kb]));   // forbid remat-as-load
        asm volatile("" : "+v"(B2[kb]));
    }
    const float cv = c1[e * 256 + j];
    const float bv = b2[e * 256 + j];

    __shared__ int toks[16];
    __shared__ unsigned short Ab[4096];    // [kb][lane][8] bf16, 8 KB
    __shared__ unsigned short Hb[4096];    // 8 KB

    for (int m0 = slot * 16; m0 < n_e; m0 += 64) {
        const int mact = min(16, n_e - m0);
        __syncthreads();                   // toks reuse guard across tiles
        if (t < 16)
            toks[t] = (t < mact) ? lists[(hop * NEXP + e) * NTOK + m0 + t] : 0;
        __syncthreads();

        // ---- stage A tile: src rows (f32) -> bf16 in A-frag layout ----
        {
            int m = t >> 6;                // token row 0..15 (one wave per row)
            int k = (t & 63) * 4;          // float4 column
            float4 v = make_float4(0.f, 0.f, 0.f, 0.f);
            if (m < mact) v = *(const float4*)(src + toks[m] * 256 + k);
            int kb = k >> 5, gg = (k >> 3) & 3, i = k & 7;
            unsigned short* d = Ab + kb * 512 + (gg * 16 + m) * 8 + i;
            d[0] = f2bf(v.x); d[1] = f2bf(v.y); d[2] = f2bf(v.z); d[3] = f2bf(v.w);
        }
        __syncthreads();

        // ---- GEMM1 (weights in registers) ----
        floatx4 acc = (floatx4){cv, cv, cv, cv};
        #pragma unroll
        for (int kb = 0; kb < 8; kb++) {
            short8 a = *(const short8*)(Ab + kb * 512 + l * 8);
            acc = __builtin_amdgcn_mfma_f32_16x16x32_bf16(a, B1[kb], acc, 0, 0, 0);
        }
        // ---- epilogue 1: relu -> Hb in A-frag layout (h-dim becomes K) ----
        {
            int kb2 = j >> 5, g2 = (j >> 3) & 3, i2 = j & 7;
            #pragma unroll
            for (int r = 0; r < 4; r++) {
                int m = g * 4 + r;         // D row (token)
                float vv = acc[r];
                vv = vv > 0.f ? vv : 0.f;
                Hb[kb2 * 512 + (g2 * 16 + m) * 8 + i2] = f2bf(vv);
            }
        }
        __syncthreads();

        // ---- GEMM2 ----
        floatx4 acc2 = (floatx4){bv, bv, bv, bv};
        #pragma unroll
        for (int kb = 0; kb < 8; kb++) {
            short8 a = *(const short8*)(Hb + kb * 512 + l * 8);
            acc2 = __builtin_amdgcn_mfma_f32_16x16x32_bf16(a, B2[kb], acc2, 0, 0, 0);
        }
        // ---- epilogue 2: relu -> state (f32), only real rows ----
        #pragma unroll
        for (int r = 0; r < 4; r++) {
            int m = g * 4 + r;
            if (m < mact) {
                float vv = acc2[r];
                state[toks[m] * 256 + j] = vv > 0.f ? vv : 0.f;
            }
        }
    }
}

// ---------------------------------------------------------------------------
// FINAL: mean-pool 8 patches -> LayerNorm -> 10-class head. One block/batch.
// Per-token source select: tokens halted at hop 0 (tempers[0][n]==12) were
// never written to state -> read x instead.
// ---------------------------------------------------------------------------
__global__ __launch_bounds__(256) void final_kernel(
    const float* __restrict__ x, const float* __restrict__ state,
    const int* __restrict__ tempers,
    const float* __restrict__ ln_g, const float* __restrict__ ln_b,
    const float* __restrict__ Wt, const float* __restrict__ bt,
    float* __restrict__ out)
{
    const int b = blockIdx.x, t = threadIdx.x;
    float s = 0.f;
    #pragma unroll
    for (int p = 0; p < 8; p++) {
        int n = b * 8 + p;
        const float* rowsrc = (tempers[n] != 12) ? state : x;
        s += rowsrc[n * 256 + t];
    }
    s *= 0.125f;

    float v1 = s, v2 = s * s;
    #pragma unroll
    for (int off = 32; off; off >>= 1) {
        v1 += __shfl_down(v1, off);
        v2 += __shfl_down(v2, off);
    }
    __shared__ float red[8];
    __shared__ float stats[2];
    const int w = t >> 6, l = t & 63;
    if (l == 0) { red[w] = v1; red[4 + w] = v2; }
    __syncthreads();
    if (t == 0) {
        float su = red[0] + red[1] + red[2] + red[3];
        float sq = red[4] + red[5] + red[6] + red[7];
        float mu = su * (1.0f / 256.0f);
        float var = sq * (1.0f / 256.0f) - mu * mu;
        stats[0] = mu;
        stats[1] = rsqrtf(var + 1e-5f);
    }
    __syncthreads();
    float normed = (s - stats[0]) * stats[1] * ln_g[t] + ln_b[t];

    __shared__ float pr[40];
    #pragma unroll
    for (int c = 0; c < 10; c++) {
        float pv = normed * Wt[t * 10 + c];
        #pragma unroll
        for (int off = 32; off; off >>= 1) pv += __shfl_down(pv, off);
        if (l == 0) pr[w * 10 + c] = pv;
    }
    __syncthreads();
    if (t < 10)
        out[b * 10 + t] = pr[t] + pr[10 + t] + pr[20 + t] + pr[30 + t] + bt[t];
}

extern "C" void kernel_launch(void* const* d_in, const int* in_sizes, int n_in,
                              void* d_out, int out_size, void* d_ws, size_t ws_size,
                              hipStream_t stream)
{
    const float* x      = (const float*)d_in[0];
    const float* W1     = (const float*)d_in[1];
    const float* b1     = (const float*)d_in[2];
    const float* W2     = (const float*)d_in[3];
    const float* b2     = (const float*)d_in[4];
    const float* op_emb = (const float*)d_in[5];
    const float* ln_g   = (const float*)d_in[6];
    const float* ln_b   = (const float*)d_in[7];
    const float* Wt     = (const float*)d_in[8];
    const float* bt     = (const float*)d_in[9];
    const int* tempers  = (const int*)d_in[10];
    const int* ops      = (const int*)d_in[11];

    char* ws = (char*)d_ws;
    float* state          = (float*)(ws + OFF_STATE);
    unsigned short* W1b   = (unsigned short*)(ws + OFF_W1B);
    unsigned short* W2b   = (unsigned short*)(ws + OFF_W2B);
    float* c1             = (float*)(ws + OFF_C1);
    int* counts           = (int*)(ws + OFF_COUNTS);
    int* lists            = (int*)(ws + OFF_LISTS);
    float* out            = (float*)d_out;

    prep_kernel<<<2917, 256, 0, stream>>>(W1, b1, W2, op_emb, tempers, ops,
                                          W1b, W2b, c1, counts, lists);
    for (int hop = 0; hop < HOPS; hop++)
        hop_kernel<<<160, 1024, 0, stream>>>(hop == 0 ? x : state, state,
                                             W1b, W2b, c1, b2,
                                             counts, lists, hop);
    final_kernel<<<128, 256, 0, stream>>>(x, state, tempers,
                                          ln_g, ln_b, Wt, bt, out);
}

// Round 4
// 135.364 us; speedup vs baseline: 2.1585x; 1.0204x over previous
//
#include <hip/hip_runtime.h>

typedef __attribute__((ext_vector_type(8))) short short8;
typedef __attribute__((ext_vector_type(4))) float floatx4;

// Problem constants
#define NEXP   36          // 12 tempers * 3 ops
#define NTOK   1024        // 128 batch * 8 patches
#define HOPS   4

// Workspace layout (bytes)
#define OFF_STATE   0u          // 1024*256*4      = 1,048,576
#define OFF_W1B     1048576u    // 36*65536*2      = 4,718,592 (bf16, B-frag swizzled)
#define OFF_W2B     5767168u    // 36*65536*2      = 4,718,592
#define OFF_C1      10485760u   // 36*256*4        = 36,864
#define OFF_COUNTS  10522624u   // 4*36*4          = 576
#define OFF_LISTS   10523264u   // 4*36*1024*4     = 589,824
#define OFF_VER     11113088u   // 1024*4          = 4,096  (end ~11.12 MB)

__device__ __forceinline__ unsigned short f2bf(float f) {
    unsigned u = __float_as_uint(f);
    u += 0x7FFFu + ((u >> 16) & 1u);   // round-to-nearest-even
    return (unsigned short)(u >> 16);
}

// ---------------------------------------------------------------------------
// PREP (unchanged from r3 except: routing block also zeroes ver[]).
// XCD-affinity: every block touching expert e satisfies bid%8 == e%8.
//  bids [0,2880)   : weight convert (r=bid%8, q=bid/8, e=r+8*(q/64)).
//  bids [2880,2916): c1[e].
//  bid  2916       : routing + ver[] zeroing.
// ---------------------------------------------------------------------------
__global__ __launch_bounds__(256) void prep_kernel(
    const float* __restrict__ W1, const float* __restrict__ b1,
    const float* __restrict__ W2, const float* __restrict__ op_emb,
    const int* __restrict__ tempers, const int* __restrict__ ops,
    unsigned short* __restrict__ W1b, unsigned short* __restrict__ W2b,
    float* __restrict__ c1, int* __restrict__ counts, int* __restrict__ lists,
    int* __restrict__ ver)
{
    const int bid = blockIdx.x;
    const int t = threadIdx.x;

    if (bid < 2880) {
        // ---- weight convert + swizzle (XCD-affine) ----
        const int r  = bid & 7;
        const int q  = bid >> 3;
        const int e  = r + 8 * (q >> 6);
        if (e >= NEXP) return;
        const int sub = q & 63;
        const int mat = sub >> 5;          // 0: W1, 1: W2
        const int s2  = sub & 31;
        const int kb  = s2 >> 2;
        const int jt  = s2 & 3;
        const float* src = mat ? (W2 + e * 65536) : (W1 + e * 98304);
        unsigned short* dst = (mat ? W2b : W1b) + e * 65536;
        const int j  = jt * 64 + (t & 63);
        const int ks = (t >> 6) * 8;       // 8 consecutive k per thread
        short8 v;
        #pragma unroll
        for (int i = 0; i < 8; i++)
            v[i] = (short)f2bf(src[(kb * 32 + ks + i) * 256 + j]);  // coalesced across j
        *(short8*)(dst + (kb * 256 + j) * 32 + ks) = v;
    } else if (bid < 2916) {
        // ---- c1 precompute (fp32), XCD-affine ----
        const int e = bid - 2880;
        __shared__ float eb[128];
        if (t < 128) eb[t] = op_emb[e * 128 + t];
        __syncthreads();
        float acc = b1[e * 256 + t];
        const float* wp = W1 + e * 98304 + 65536;  // emb rows of W1[e]
        #pragma unroll 4
        for (int k = 0; k < 128; k++)
            acc += eb[k] * wp[k * 256 + t];
        c1[e * 256 + t] = acc;
    } else {
        // ---- routing (single block; cumulative-halt semantics) ----
        __shared__ int lc[HOPS * NEXP];
        if (t < HOPS * NEXP) lc[t] = 0;
        for (int i = t; i < NTOK; i += 256) ver[i] = 0;   // token version ctrs
        __syncthreads();
        for (int q = 0; q < 4; q++) {
            int n = q * 256 + t;
            bool act = true;
            for (int hop = 0; hop < HOPS; hop++) {
                int tt = tempers[hop * NTOK + n];
                int oo = ops[hop * NTOK + n];
                act = act && (tt != 12);       // 12 == halt; sticky
                if (act) {
                    int e = tt * 3 + oo;
                    int pos = atomicAdd(&lc[hop * NEXP + e], 1);
                    lists[(hop * NEXP + e) * NTOK + pos] = n;
                }
            }
        }
        __syncthreads();
        if (t < HOPS * NEXP) counts[t] = lc[t];
    }
}

// ---------------------------------------------------------------------------
// MEGA-HOP: ALL FOUR HOPS in one launch, synchronized per-token.
// Sticky halt => token in hop-h list was active at hops 0..h-1, so it has
// received exactly h state writes. ver[tok] counts completed updates:
// hop-h consumer spins until ver[tok] >= h. Dependencies are strictly
// hop-ordered (every block finishes its hop h-1 tiles before any hop-h spin
// in program order), and all 160 blocks are co-resident (<=256 CUs), so the
// spin is deadlock-free WITHOUT cooperative launch.
// Coherence protocol (per-XCD L2s are not coherent):
//   producer: stores -> __syncthreads (drains vmcnt: stores in L2)
//             -> t0 __threadfence (device-scope L2 writeback) -> barrier
//             -> RELEASE fetch_add ver[tok]
//   consumer: relaxed spin on ver -> ACQUIRE reload (invalidates L1/L2)
//             -> barrier -> read state
// B-frags preloaded ONCE into registers and reused across all 4 hops (the
// r1/r2 fusion goal, without grid.sync). Weights/c1/b2 are register-resident
// so the acquire invalidations cost nothing.
// bid -> e = bid%40 (bid%8==e%8 matches prep's XCD-affine writes),
// slot = bid/40; slot s handles tiles m0 = s*16 + k*64.
// MFMA maps (m89): A[m=l&15][k=(l>>4)*8+i]; D col=l&15, row=(l>>4)*4+reg.
// ---------------------------------------------------------------------------
__global__ __launch_bounds__(1024, 4) void mega_hop_kernel(
    const float* __restrict__ x, float* __restrict__ state,
    const unsigned short* __restrict__ W1b,
    const unsigned short* __restrict__ W2b,
    const float* __restrict__ c1, const float* __restrict__ b2,
    const int* __restrict__ counts, const int* __restrict__ lists,
    int* __restrict__ ver)
{
    const int e    = blockIdx.x % 40;
    const int slot = blockIdx.x / 40;
    if (e >= NEXP) return;

    int ne[HOPS];
    bool any = false;
    #pragma unroll
    for (int h = 0; h < HOPS; h++) {
        ne[h] = counts[h * NEXP + e];
        any = any || (slot * 16 < ne[h]);
    }
    if (!any) return;                      // no tile in any hop for this slot

    const int t = threadIdx.x;
    const int l = t & 63, w = t >> 6;      // wave 0..15
    const int col = l & 15, g = l >> 4;
    const int j = w * 16 + col;            // this wave's output column

    // ---- preload B-frags ONCE for all hops (register-resident) ----
    const unsigned short* Wp  = W1b + e * 65536;
    const unsigned short* Wp2 = W2b + e * 65536;
    short8 B1[8], B2[8];
    #pragma unroll
    for (int kb = 0; kb < 8; kb++) {
        B1[kb] = *(const short8*)(Wp  + (kb * 256 + j) * 32 + g * 8);
        B2[kb] = *(const short8*)(Wp2 + (kb * 256 + j) * 32 + g * 8);
    }
    #pragma unroll
    for (int kb = 0; kb < 8; kb++) {
        asm volatile("" : "+v"(B1[kb]));   // forbid remat-as-load
        asm volatile("" : "+v"(B2[kb]));
    }
    const float cv = c1[e * 256 + j];
    const float bv = b2[e * 256 + j];

    __shared__ int toks[16];
    __shared__ unsigned short Ab[4096];    // [kb][lane][8] bf16, 8 KB
    __shared__ unsigned short Hb[4096];    // 8 KB

    for (int hop = 0; hop < HOPS; hop++) {
        const float* src = hop ? state : x;
        for (int m0 = slot * 16; m0 < ne[hop]; m0 += 64) {
            const int mact = min(16, ne[hop] - m0);
            __syncthreads();               // toks/Ab reuse guard
            if (t < 16) {
                int tok = (t < mact)
                        ? lists[(hop * NEXP + e) * NTOK + m0 + t] : -1;
                toks[t] = tok;
                if (hop > 0 && tok >= 0) {
                    // wait for this token's hop-(h-1) state write
                    while (__hip_atomic_load(&ver[tok], __ATOMIC_RELAXED,
                                             __HIP_MEMORY_SCOPE_AGENT) < hop)
                        __builtin_amdgcn_s_sleep(1);
                    (void)__hip_atomic_load(&ver[tok], __ATOMIC_ACQUIRE,
                                            __HIP_MEMORY_SCOPE_AGENT);
                }
            }
            __syncthreads();

            // ---- stage A tile: src rows (f32) -> bf16 in A-frag layout ----
            {
                int m = t >> 6;            // token row 0..15 (one wave per row)
                int k = (t & 63) * 4;      // float4 column
                float4 v = make_float4(0.f, 0.f, 0.f, 0.f);
                if (m < mact) v = *(const float4*)(src + toks[m] * 256 + k);
                int kb = k >> 5, gg = (k >> 3) & 3, i = k & 7;
                unsigned short* d = Ab + kb * 512 + (gg * 16 + m) * 8 + i;
                d[0] = f2bf(v.x); d[1] = f2bf(v.y);
                d[2] = f2bf(v.z); d[3] = f2bf(v.w);
            }
            __syncthreads();

            // ---- GEMM1 (weights in registers) ----
            floatx4 acc = (floatx4){cv, cv, cv, cv};
            #pragma unroll
            for (int kb = 0; kb < 8; kb++) {
                short8 a = *(const short8*)(Ab + kb * 512 + l * 8);
                acc = __builtin_amdgcn_mfma_f32_16x16x32_bf16(a, B1[kb], acc, 0, 0, 0);
            }
            // ---- epilogue 1: relu -> Hb in A-frag layout ----
            {
                int kb2 = j >> 5, g2 = (j >> 3) & 3, i2 = j & 7;
                #pragma unroll
                for (int r = 0; r < 4; r++) {
                    int m = g * 4 + r;
                    float vv = acc[r];
                    vv = vv > 0.f ? vv : 0.f;
                    Hb[kb2 * 512 + (g2 * 16 + m) * 8 + i2] = f2bf(vv);
                }
            }
            __syncthreads();

            // ---- GEMM2 ----
            floatx4 acc2 = (floatx4){bv, bv, bv, bv};
            #pragma unroll
            for (int kb = 0; kb < 8; kb++) {
                short8 a = *(const short8*)(Hb + kb * 512 + l * 8);
                acc2 = __builtin_amdgcn_mfma_f32_16x16x32_bf16(a, B2[kb], acc2, 0, 0, 0);
            }
            // ---- epilogue 2: relu -> state (f32), only real rows ----
            #pragma unroll
            for (int r = 0; r < 4; r++) {
                int m = g * 4 + r;
                if (m < mact) {
                    float vv = acc2[r];
                    state[toks[m] * 256 + j] = vv > 0.f ? vv : 0.f;
                }
            }

            // ---- publish: make rows device-visible, bump version ----
            if (hop < HOPS - 1) {          // hop3 consumed after kernel end
                __syncthreads();           // drain all waves' stores into L2
                if (t == 0) __threadfence();   // device-scope L2 writeback
                __syncthreads();
                if (t < mact)
                    __hip_atomic_fetch_add(&ver[toks[t]], 1, __ATOMIC_RELEASE,
                                           __HIP_MEMORY_SCOPE_AGENT);
            }
        }
    }
}

// ---------------------------------------------------------------------------
// FINAL: mean-pool 8 patches -> LayerNorm -> 10-class head. One block/batch.
// Tokens halted at hop 0 were never written to state -> read x instead.
// ---------------------------------------------------------------------------
__global__ __launch_bounds__(256) void final_kernel(
    const float* __restrict__ x, const float* __restrict__ state,
    const int* __restrict__ tempers,
    const float* __restrict__ ln_g, const float* __restrict__ ln_b,
    const float* __restrict__ Wt, const float* __restrict__ bt,
    float* __restrict__ out)
{
    const int b = blockIdx.x, t = threadIdx.x;
    float s = 0.f;
    #pragma unroll
    for (int p = 0; p < 8; p++) {
        int n = b * 8 + p;
        const float* rowsrc = (tempers[n] != 12) ? state : x;
        s += rowsrc[n * 256 + t];
    }
    s *= 0.125f;

    float v1 = s, v2 = s * s;
    #pragma unroll
    for (int off = 32; off; off >>= 1) {
        v1 += __shfl_down(v1, off);
        v2 += __shfl_down(v2, off);
    }
    __shared__ float red[8];
    __shared__ float stats[2];
    const int w = t >> 6, l = t & 63;
    if (l == 0) { red[w] = v1; red[4 + w] = v2; }
    __syncthreads();
    if (t == 0) {
        float su = red[0] + red[1] + red[2] + red[3];
        float sq = red[4] + red[5] + red[6] + red[7];
        float mu = su * (1.0f / 256.0f);
        float var = sq * (1.0f / 256.0f) - mu * mu;
        stats[0] = mu;
        stats[1] = rsqrtf(var + 1e-5f);
    }
    __syncthreads();
    float normed = (s - stats[0]) * stats[1] * ln_g[t] + ln_b[t];

    __shared__ float pr[40];
    #pragma unroll
    for (int c = 0; c < 10; c++) {
        float pv = normed * Wt[t * 10 + c];
        #pragma unroll
        for (int off = 32; off; off >>= 1) pv += __shfl_down(pv, off);
        if (l == 0) pr[w * 10 + c] = pv;
    }
    __syncthreads();
    if (t < 10)
        out[b * 10 + t] = pr[t] + pr[10 + t] + pr[20 + t] + pr[30 + t] + bt[t];
}

extern "C" void kernel_launch(void* const* d_in, const int* in_sizes, int n_in,
                              void* d_out, int out_size, void* d_ws, size_t ws_size,
                              hipStream_t stream)
{
    const float* x      = (const float*)d_in[0];
    const float* W1     = (const float*)d_in[1];
    const float* b1     = (const float*)d_in[2];
    const float* W2     = (const float*)d_in[3];
    const float* b2     = (const float*)d_in[4];
    const float* op_emb = (const float*)d_in[5];
    const float* ln_g   = (const float*)d_in[6];
    const float* ln_b   = (const float*)d_in[7];
    const float* Wt     = (const float*)d_in[8];
    const float* bt     = (const float*)d_in[9];
    const int* tempers  = (const int*)d_in[10];
    const int* ops      = (const int*)d_in[11];

    char* ws = (char*)d_ws;
    float* state          = (float*)(ws + OFF_STATE);
    unsigned short* W1b   = (unsigned short*)(ws + OFF_W1B);
    unsigned short* W2b   = (unsigned short*)(ws + OFF_W2B);
    float* c1             = (float*)(ws + OFF_C1);
    int* counts           = (int*)(ws + OFF_COUNTS);
    int* lists            = (int*)(ws + OFF_LISTS);
    int* ver              = (int*)(ws + OFF_VER);
    float* out            = (float*)d_out;

    prep_kernel<<<2917, 256, 0, stream>>>(W1, b1, W2, op_emb, tempers, ops,
                                          W1b, W2b, c1, counts, lists, ver);
    mega_hop_kernel<<<160, 1024, 0, stream>>>(x, state, W1b, W2b, c1, b2,
                                              counts, lists, ver);
    final_kernel<<<128, 256, 0, stream>>>(x, state, tempers,
                                          ln_g, ln_b, Wt, bt, out);
}